// Round 1
// baseline (200.025 us; speedup 1.0000x reference)
//
#include <hip/hip_runtime.h>

// DropStripes: out = in * keep, keep(b,t) = !any_s( bgns[b,s] <= t < bgns[b,s]+dist[b,s] )
// Shapes: input (B=64, C=8, T=2048, F=128) fp32; distances (B,2) i32; bgns (B,2) i32.

constexpr int Bn = 64;
constexpr int Cn = 8;
constexpr int Tn = 2048;   // power of two -> mask
constexpr int Fn = 128;    // 32 float4 per row
constexpr int STRIPES = 2;

__global__ __launch_bounds__(256) void
drop_stripes_kernel(const float4* __restrict__ in,
                    const int* __restrict__ distances,
                    const int* __restrict__ bgns,
                    float4* __restrict__ out,
                    int n4)
{
    int idx = blockIdx.x * blockDim.x + threadIdx.x;
    const int stride = gridDim.x * blockDim.x;

    for (; idx < n4; idx += stride) {
        // flat float4 index -> (b, c, t, f4): row = (b*C + c)*T + t
        const int row = idx >> 5;            // / (F/4 = 32)
        const int t   = row & (Tn - 1);      // % T
        const int b   = row >> 14;           // / (T*C) = / 16384

        const int s0 = bgns[b * STRIPES + 0];
        const int s1 = bgns[b * STRIPES + 1];
        const int d0 = distances[b * STRIPES + 0];
        const int d1 = distances[b * STRIPES + 1];

        const bool drop = ((unsigned)(t - s0) < (unsigned)d0) |
                          ((unsigned)(t - s1) < (unsigned)d1);

        if (drop) {
            out[idx] = make_float4(0.f, 0.f, 0.f, 0.f);
        } else {
            out[idx] = in[idx];
        }
    }
}

extern "C" void kernel_launch(void* const* d_in, const int* in_sizes, int n_in,
                              void* d_out, int out_size, void* d_ws, size_t ws_size,
                              hipStream_t stream)
{
    const float4* in        = (const float4*)d_in[0];
    const int*    distances = (const int*)d_in[1];
    const int*    bgns      = (const int*)d_in[2];
    float4*       out       = (float4*)d_out;

    const int n4 = out_size / 4;   // 33,554,432 float4

    const int block = 256;
    const int grid  = 8192;        // grid-stride; multiple of 8 XCDs

    drop_stripes_kernel<<<grid, block, 0, stream>>>(in, distances, bgns, out, n4);
}

// Round 3
// 191.643 us; speedup vs baseline: 1.0437x; 1.0437x over previous
//
#include <hip/hip_runtime.h>

// DropStripes: out = in * keep, keep(b,t) = !any_s( bgns[b,s] <= t < bgns[b,s]+dist[b,s] )
// Shapes: input (B=64, C=8, T=2048, F=128) fp32; distances (B,2) i32; bgns (B,2) i32.
// Pure streaming masked copy: 512 MiB in + 512 MiB out, memory-bound.

typedef float f4 __attribute__((ext_vector_type(4)));  // clang vector: valid for nontemporal builtins

constexpr int Bn = 64;
constexpr int Cn = 8;
constexpr int Tn = 2048;    // power of two -> mask
constexpr int Fn = 128;     // 32 float4 per row
constexpr int STRIPES = 2;

constexpr int N4_PER_B     = Cn * Tn * (Fn / 4);      // 524288 f4 per batch
constexpr int BLOCKS_PER_B = 128;                     // b is block-uniform
constexpr int CHUNK        = N4_PER_B / BLOCKS_PER_B; // 4096 f4 per block
constexpr int BLOCK        = 256;
constexpr int ITERS        = CHUNK / BLOCK;           // 16, tail-free

__global__ __launch_bounds__(BLOCK) void
drop_stripes_kernel(const f4* __restrict__ in,
                    const int* __restrict__ distances,
                    const int* __restrict__ bgns,
                    f4* __restrict__ out)
{
    const int b     = blockIdx.x >> 7;                  // / BLOCKS_PER_B (uniform)
    const int chunk = blockIdx.x & (BLOCKS_PER_B - 1);
    const int base  = b * N4_PER_B + chunk * CHUNK;

    // Block-uniform -> compiler emits scalar loads, once per block.
    const int s0 = bgns[b * STRIPES + 0];
    const int s1 = bgns[b * STRIPES + 1];
    const int d0 = distances[b * STRIPES + 0];
    const int d1 = distances[b * STRIPES + 1];

    #pragma unroll
    for (int i = 0; i < ITERS; i += 4) {
        int idx0 = base + (i + 0) * BLOCK + threadIdx.x;
        int idx1 = base + (i + 1) * BLOCK + threadIdx.x;
        int idx2 = base + (i + 2) * BLOCK + threadIdx.x;
        int idx3 = base + (i + 3) * BLOCK + threadIdx.x;

        // 4 independent loads in flight per thread.
        f4 v0 = __builtin_nontemporal_load(&in[idx0]);
        f4 v1 = __builtin_nontemporal_load(&in[idx1]);
        f4 v2 = __builtin_nontemporal_load(&in[idx2]);
        f4 v3 = __builtin_nontemporal_load(&in[idx3]);

        const int t0 = (idx0 >> 5) & (Tn - 1);
        const int t1 = (idx1 >> 5) & (Tn - 1);
        const int t2 = (idx2 >> 5) & (Tn - 1);
        const int t3 = (idx3 >> 5) & (Tn - 1);

        const bool k0 = ((unsigned)(t0 - s0) >= (unsigned)d0) & ((unsigned)(t0 - s1) >= (unsigned)d1);
        const bool k1 = ((unsigned)(t1 - s0) >= (unsigned)d0) & ((unsigned)(t1 - s1) >= (unsigned)d1);
        const bool k2 = ((unsigned)(t2 - s0) >= (unsigned)d0) & ((unsigned)(t2 - s1) >= (unsigned)d1);
        const bool k3 = ((unsigned)(t3 - s0) >= (unsigned)d0) & ((unsigned)(t3 - s1) >= (unsigned)d1);

        const f4 z = (f4)(0.f);
        f4 r0 = k0 ? v0 : z;
        f4 r1 = k1 ? v1 : z;
        f4 r2 = k2 ? v2 : z;
        f4 r3 = k3 ? v3 : z;

        __builtin_nontemporal_store(r0, &out[idx0]);
        __builtin_nontemporal_store(r1, &out[idx1]);
        __builtin_nontemporal_store(r2, &out[idx2]);
        __builtin_nontemporal_store(r3, &out[idx3]);
    }
}

extern "C" void kernel_launch(void* const* d_in, const int* in_sizes, int n_in,
                              void* d_out, int out_size, void* d_ws, size_t ws_size,
                              hipStream_t stream)
{
    const f4* in        = (const f4*)d_in[0];
    const int* distances = (const int*)d_in[1];
    const int* bgns      = (const int*)d_in[2];
    f4* out              = (f4*)d_out;

    const int grid = Bn * BLOCKS_PER_B;   // 8192 blocks, tail-free

    drop_stripes_kernel<<<grid, BLOCK, 0, stream>>>(in, distances, bgns, out);
}